// Round 1
// baseline (527.518 us; speedup 1.0000x reference)
//
#include <hip/hip_runtime.h>

#define R 256
#define C 32

// Convert + transpose: (3, C, R, R) f32 -> (3, R, R, C) bf16 (stored as ushort).
// One block per (p, y) row; thread t = x. Reads coalesced (1 KB per c across
// the block); each thread writes its 64 B channel vector with 16 B stores.
__global__ __launch_bounds__(256) void convert_kernel(const float* __restrict__ tri,
                                                      ushort* __restrict__ tw) {
    int p = blockIdx.x >> 8;        // blockIdx.x = p*R + y
    int y = blockIdx.x & (R - 1);
    int x = threadIdx.x;

    unsigned packed[C / 2];         // 16 dwords = 32 bf16
#pragma unroll
    for (int i = 0; i < C / 2; ++i) {
        unsigned w = 0;
#pragma unroll
        for (int h = 0; h < 2; ++h) {
            float f = tri[(((p * C + (2 * i + h)) * R) + y) * R + x];
            unsigned u = __float_as_uint(f);
            // round-to-nearest-even bf16
            unsigned r = (u + 0x7fffu + ((u >> 16) & 1u)) >> 16;
            w |= (r & 0xffffu) << (16 * h);
        }
        packed[i] = w;
    }
    uint4* dst = (uint4*)(tw + ((size_t)(p * R + y) * R + x) * C);
#pragma unroll
    for (int i = 0; i < 4; ++i) {
        dst[i] = make_uint4(packed[4 * i], packed[4 * i + 1],
                            packed[4 * i + 2], packed[4 * i + 3]);
    }
}

// One tap's 8 channels (4 dwords of packed bf16) into 8 accumulators.
__device__ __forceinline__ void tap_fma(uint4 v, float w, float* acc) {
    unsigned d[4] = {v.x, v.y, v.z, v.w};
#pragma unroll
    for (int k = 0; k < 4; ++k) {
        // bf16 -> f32 is exact: low half -> even channel, high -> odd channel
        acc[2 * k]     = fmaf(w, __uint_as_float(d[k] << 16),          acc[2 * k]);
        acc[2 * k + 1] = fmaf(w, __uint_as_float(d[k] & 0xffff0000u), acc[2 * k + 1]);
    }
}

// One point per 4 lanes; lane handles channel octet [8*cq, 8*cq+8) via a
// single bf16x8 (16 B, dwordx4) load per tap. Each tap is still one 64 B
// texel vector per point (same line footprint as before), but coord/address
// math is replicated 4x instead of 16x and VMEM instruction count per point
// drops ~4x. Output: 2 x float4 per lane, 128 B coalesced per point.
__global__ __launch_bounds__(256) void sample_kernel(const float* __restrict__ xyz,
                                                     const ushort* __restrict__ tw,
                                                     float* __restrict__ out, int M) {
    int tid = blockIdx.x * 256 + threadIdx.x;
    int q   = tid >> 2;             // point stream
    int cq  = tid & 3;              // channel-octet index
    int nq  = (gridDim.x * 256) >> 2;

    const ushort* twc = tw + 8 * cq;    // 16 B channel offset for this lane

    for (int m = q; m < M; m += nq) {
        // Same address across the 4-lane group -> broadcast from cache.
        float px = xyz[3 * m + 0];
        float py = xyz[3 * m + 1];
        float pz = xyz[3 * m + 2];

        // plane p: ix from uu, iy from vv (projection = axis permutation)
        float uu[3] = {py, pz, py};
        float vv[3] = {px, px, pz};

        float acc[8];
#pragma unroll
        for (int j = 0; j < 8; ++j) acc[j] = 0.0f;

#pragma unroll
        for (int p = 0; p < 3; ++p) {
            float ix = (uu[p] + 1.0f) * 0.5f * 255.0f;
            float iy = (vv[p] + 1.0f) * 0.5f * 255.0f;
            // ix, iy >= 0 here, so int truncation == floor (saves v_floor)
            int   x0  = (int)ix;
            int   y0  = (int)iy;
            float wx1 = ix - (float)x0;
            float wy1 = iy - (float)y0;
            float wx0 = 1.0f - wx1;
            float wy0 = 1.0f - wy1;
            // xyz in [-1,1): x1 can only hit R when its weight is exactly 0,
            // so clamping matches padding_mode='zeros'.
            int x1 = min(x0 + 1, R - 1);
            int y1 = min(y0 + 1, R - 1);

            float w00 = wx0 * wy0;
            float w01 = wx1 * wy0;
            float w10 = wx0 * wy1;
            float w11 = wx1 * wy1;

            const ushort* pl = twc + (size_t)p * R * R * C;
            uint4 v00 = *(const uint4*)(pl + (y0 * R + x0) * C);
            uint4 v01 = *(const uint4*)(pl + (y0 * R + x1) * C);
            uint4 v10 = *(const uint4*)(pl + (y1 * R + x0) * C);
            uint4 v11 = *(const uint4*)(pl + (y1 * R + x1) * C);

            tap_fma(v00, w00, acc);
            tap_fma(v01, w01, acc);
            tap_fma(v10, w10, acc);
            tap_fma(v11, w11, acc);
        }

        float4* o = (float4*)(out + (size_t)m * C + 8 * cq);
        o[0] = make_float4(acc[0], acc[1], acc[2], acc[3]);
        o[1] = make_float4(acc[4], acc[5], acc[6], acc[7]);
    }
}

extern "C" void kernel_launch(void* const* d_in, const int* in_sizes, int n_in,
                              void* d_out, int out_size, void* d_ws, size_t ws_size,
                              hipStream_t stream) {
    const float* xyz = (const float*)d_in[0];
    const float* tri = (const float*)d_in[1];  // (3, C, R, R) f32
    float* out = (float*)d_out;                // (M, C) f32
    ushort* tw = (ushort*)d_ws;                // (3, R, R, C) bf16, 12 MiB

    int M = in_sizes[0] / 3;

    convert_kernel<<<3 * R, 256, 0, stream>>>(tri, tw);

    // 4096 blocks * 64 point-streams/block = 262144 streams, 8 pts each
    sample_kernel<<<4096, 256, 0, stream>>>(xyz, tw, out, M);
}